// Round 1
// baseline (346.070 us; speedup 1.0000x reference)
//
#include <hip/hip_runtime.h>

// Problem constants (fixed by reference setup_inputs)
#define BT    16384          // b*t = 4*4096
#define TSEQ  4096           // time steps per batch
#define DM    1024           // d_model
#define EXP   1024           // expanded
#define N1    2048           // 2*EXP
#define KDIM  1024           // GEMM K (both GEMMs)
#define EPSV  1e-8f

typedef __bf16 bf16x8 __attribute__((ext_vector_type(8)));
typedef float f32x4 __attribute__((ext_vector_type(4)));
typedef unsigned short u16x8 __attribute__((ext_vector_type(8)));

#define AS1CAST(p) ((__attribute__((address_space(1))) void*)(p))
#define AS3CAST(p) ((__attribute__((address_space(3))) void*)(p))

__device__ __forceinline__ unsigned short f2bf(float f) {
    unsigned int u = __float_as_uint(f);
    u += 0x7fffu + ((u >> 16) & 1u);
    return (unsigned short)(u >> 16);
}

// ---------------------------------------------------------------------------
// fp32 -> bf16 conversion, 4 elems/thread
__global__ __launch_bounds__(256) void k_f2bf(const float* __restrict__ in,
                                              unsigned short* __restrict__ out,
                                              int n4) {
    int i = blockIdx.x * 256 + threadIdx.x;
    if (i >= n4) return;
    float4 v = ((const float4*)in)[i];
    ushort4 o;
    o.x = f2bf(v.x); o.y = f2bf(v.y); o.z = f2bf(v.z); o.w = f2bf(v.w);
    ((ushort4*)out)[i] = o;
}

// ---------------------------------------------------------------------------
// m97-style bf16 GEMM, C[m,n] = sum_k A[m,k]*B[n,k] + bias[n]
// 128x128 tile / block (256 thr = 4 waves, each wave 64x64 via 4x4 MFMA grid).
// Epilogue: per-row sumsq (shuffle-reduce + atomicAdd) for downstream RMSNorm.
template <int BF16_OUT>
__global__ __launch_bounds__(256) void k_gemm(const unsigned short* __restrict__ A,
                                              const unsigned short* __restrict__ Bw,
                                              const float* __restrict__ bias,
                                              unsigned short* __restrict__ Cb,
                                              float* __restrict__ Cf,
                                              float* __restrict__ ssq,
                                              int N) {
    __shared__ unsigned short sA[128 * 32];
    __shared__ unsigned short sB[128 * 32];

    const int tid  = threadIdx.x;
    const int lane = tid & 63;
    const int wv   = tid >> 6;
    const int wm   = wv >> 1, wn = wv & 1;
    const int bm = blockIdx.y, bn = blockIdx.x;
    const int row0 = bm * 128, col0 = bn * 128;

    // staging: segment s in [0,512), 16B each; thread covers s=tid and s=tid+256
    const int rA = tid >> 2, cA = (tid & 3) * 8;
    const unsigned short* aP = A  + (size_t)(row0 + rA) * KDIM + cA;
    const unsigned short* bP = Bw + (size_t)(col0 + rA) * KDIM + cA;
    unsigned short* lA0 = sA + (wv * 64) * 8;         // wave-uniform LDS dests
    unsigned short* lA1 = sA + (256 + wv * 64) * 8;
    unsigned short* lB0 = sB + (wv * 64) * 8;
    unsigned short* lB1 = sB + (256 + wv * 64) * 8;

    const int lm = lane & 15, lq = lane >> 4;
    const int aoff = (wm * 64 + lm) * 32 + lq * 8;
    const int boff = (wn * 64 + lm) * 32 + lq * 8;

    f32x4 acc[4][4] = {};

    for (int kt = 0; kt < KDIM / 32; ++kt) {
        __syncthreads();
        const unsigned short* ap = aP + kt * 32;
        const unsigned short* bp = bP + kt * 32;
        __builtin_amdgcn_global_load_lds(AS1CAST(ap), AS3CAST(lA0), 16, 0, 0);
        __builtin_amdgcn_global_load_lds(AS1CAST(ap + (size_t)64 * KDIM), AS3CAST(lA1), 16, 0, 0);
        __builtin_amdgcn_global_load_lds(AS1CAST(bp), AS3CAST(lB0), 16, 0, 0);
        __builtin_amdgcn_global_load_lds(AS1CAST(bp + (size_t)64 * KDIM), AS3CAST(lB1), 16, 0, 0);
        __syncthreads();

        bf16x8 aF[4], bF[4];
#pragma unroll
        for (int i = 0; i < 4; ++i) aF[i] = *(const bf16x8*)&sA[aoff + i * 512];
#pragma unroll
        for (int j = 0; j < 4; ++j) bF[j] = *(const bf16x8*)&sB[boff + j * 512];
#pragma unroll
        for (int i = 0; i < 4; ++i)
#pragma unroll
            for (int j = 0; j < 4; ++j)
                acc[i][j] = __builtin_amdgcn_mfma_f32_16x16x32_bf16(aF[i], bF[j], acc[i][j], 0, 0, 0);
    }

    // epilogue
    const int gnb = col0 + wn * 64 + lm;
    float bs[4];
#pragma unroll
    for (int j = 0; j < 4; ++j) bs[j] = bias[gnb + j * 16];

#pragma unroll
    for (int i = 0; i < 4; ++i) {
        const int rowi = row0 + wm * 64 + i * 16 + lq * 4;
#pragma unroll
        for (int r = 0; r < 4; ++r) {
            const int gm = rowi + r;
            float v0 = acc[i][0][r] + bs[0];
            float v1 = acc[i][1][r] + bs[1];
            float v2 = acc[i][2][r] + bs[2];
            float v3 = acc[i][3][r] + bs[3];
            float p = v0 * v0 + v1 * v1 + v2 * v2 + v3 * v3;
#pragma unroll
            for (int off = 1; off < 16; off <<= 1) p += __shfl_xor(p, off, 64);
            if (lm == 0) atomicAdd(&ssq[gm], p);
            size_t base = (size_t)gm * N + gnb;
            if (BF16_OUT) {
                Cb[base]      = f2bf(v0);
                Cb[base + 16] = f2bf(v1);
                Cb[base + 32] = f2bf(v2);
                Cb[base + 48] = f2bf(v3);
            } else {
                Cf[base]      = v0;
                Cf[base + 16] = v1;
                Cf[base + 32] = v2;
                Cf[base + 48] = v3;
            }
        }
    }
}

// ---------------------------------------------------------------------------
// RMSNorm(z) -> split x|v -> depthwise conv(K=3, same, per-batch) -> gate
// 2 tokens / block; 128 threads/token; 8 channels/thread.
__global__ __launch_bounds__(256) void k_conv_gate(const unsigned short* __restrict__ z,
                                                   const float* __restrict__ ssq1,
                                                   const float* __restrict__ inw,
                                                   const float* __restrict__ cw,
                                                   const float* __restrict__ cb,
                                                   unsigned short* __restrict__ g) {
    const int tok = blockIdx.x * 2 + (threadIdx.x >> 7);
    const int e8  = (threadIdx.x & 127) * 8;
    const int t   = tok & (TSEQ - 1);

    const float rs0 = rsqrtf(ssq1[tok] * (1.0f / N1) + EPSV);
    const int tm = (t > 0) ? tok - 1 : tok;
    const int tp = (t < TSEQ - 1) ? tok + 1 : tok;
    const float rsm = (t > 0) ? rsqrtf(ssq1[tm] * (1.0f / N1) + EPSV) : 0.0f;
    const float rsp = (t < TSEQ - 1) ? rsqrtf(ssq1[tp] * (1.0f / N1) + EPSV) : 0.0f;

    bf16x8 xm = *(const bf16x8*)(z + (size_t)tm * N1 + e8);
    bf16x8 x0 = *(const bf16x8*)(z + (size_t)tok * N1 + e8);
    bf16x8 xp = *(const bf16x8*)(z + (size_t)tp * N1 + e8);
    bf16x8 vv = *(const bf16x8*)(z + (size_t)tok * N1 + EXP + e8);

    u16x8 ov;
#pragma unroll
    for (int p = 0; p < 8; ++p) {
        const int e = e8 + p;
        const float we  = inw[e];
        const float wvv = inw[EXP + e];
        const float w0 = cw[e * 3], w1 = cw[e * 3 + 1], w2 = cw[e * 3 + 2];
        float y = w0 * ((float)xm[p] * rsm * we)
                + w1 * ((float)x0[p] * rs0 * we)
                + w2 * ((float)xp[p] * rsp * we)
                + cb[e];
        float vn = (float)vv[p] * rs0 * wvv;
        ov[p] = f2bf(vn * y);
    }
    *(u16x8*)(g + (size_t)tok * EXP + e8) = ov;
}

// ---------------------------------------------------------------------------
// Final RMSNorm scale in place on fp32 output: out *= rsqrt(mean)+w
__global__ __launch_bounds__(256) void k_outnorm(float* __restrict__ o,
                                                 const float* __restrict__ ssq2,
                                                 const float* __restrict__ onw) {
    const int idx = blockIdx.x * 256 + threadIdx.x;   // one float4
    const int tok = idx >> 8;                         // 256 float4 per token
    const int d4  = (idx & 255) * 4;
    const float rs = rsqrtf(ssq2[tok] * (1.0f / DM) + EPSV);
    float4 v = ((float4*)o)[idx];
    float4 w = *(const float4*)(onw + d4);
    v.x *= rs * w.x; v.y *= rs * w.y; v.z *= rs * w.z; v.w *= rs * w.w;
    ((float4*)o)[idx] = v;
}

// ---------------------------------------------------------------------------
extern "C" void kernel_launch(void* const* d_in, const int* in_sizes, int n_in,
                              void* d_out, int out_size, void* d_ws, size_t ws_size,
                              hipStream_t stream) {
    const float* u     = (const float*)d_in[0];
    const float* W_in  = (const float*)d_in[1];
    const float* b_in  = (const float*)d_in[2];
    const float* inw   = (const float*)d_in[3];
    const float* cw    = (const float*)d_in[4];
    const float* cb    = (const float*)d_in[5];
    const float* W_out = (const float*)d_in[6];
    const float* b_out = (const float*)d_in[7];
    const float* onw   = (const float*)d_in[8];
    float* out = (float*)d_out;

    char* ws = (char*)d_ws;
    unsigned short* u_bf    = (unsigned short*)ws; ws += (size_t)BT * DM * 2;     // 32 MB
    unsigned short* Win_bf  = (unsigned short*)ws; ws += (size_t)N1 * DM * 2;     //  4 MB
    unsigned short* Wout_bf = (unsigned short*)ws; ws += (size_t)DM * EXP * 2;    //  2 MB
    unsigned short* z_bf    = (unsigned short*)ws; ws += (size_t)BT * N1 * 2;     // 64 MB
    unsigned short* g_bf    = (unsigned short*)ws; ws += (size_t)BT * EXP * 2;    // 32 MB
    float* ssq1 = (float*)ws; ws += (size_t)BT * 4;
    float* ssq2 = (float*)ws; ws += (size_t)BT * 4;

    hipMemsetAsync(ssq1, 0, (size_t)BT * 2 * sizeof(float), stream);  // ssq1+ssq2 adjacent

    k_f2bf<<<(BT * DM / 4 + 255) / 256, 256, 0, stream>>>(u, u_bf, BT * DM / 4);
    k_f2bf<<<(N1 * DM / 4 + 255) / 256, 256, 0, stream>>>(W_in, Win_bf, N1 * DM / 4);
    k_f2bf<<<(DM * EXP / 4 + 255) / 256, 256, 0, stream>>>(W_out, Wout_bf, DM * EXP / 4);

    dim3 gA(N1 / 128, BT / 128);   // (16,128)
    k_gemm<1><<<gA, 256, 0, stream>>>(u_bf, Win_bf, b_in, z_bf, nullptr, ssq1, N1);

    k_conv_gate<<<BT / 2, 256, 0, stream>>>(z_bf, ssq1, inw, cw, cb, g_bf);

    dim3 gC(DM / 128, BT / 128);   // (8,128)
    k_gemm<0><<<gC, 256, 0, stream>>>(g_bf, Wout_bf, b_out, nullptr, out, ssq2, DM);

    k_outnorm<<<BT, 256, 0, stream>>>(out, ssq2, onw);

    (void)in_sizes; (void)n_in; (void)out_size; (void)ws_size;
}